// Round 7
// baseline (264.403 us; speedup 1.0000x reference)
//
#include <hip/hip_runtime.h>
#include <math.h>

#define CH 4096        // edges per partition block
#define NBUK_MAX 256   // max buckets (N <= 131072)
#define MAXB 12288     // bucket region capacity (mean 8163, sd~90 -> 45 sigma headroom)
#define SRC_BITS 17    // N < 131072 fits in 17 bits

typedef short bf16x8 __attribute__((ext_vector_type(8)));
typedef float f32x4 __attribute__((ext_vector_type(4)));
typedef float f32x2 __attribute__((ext_vector_type(2)));

// bf16 <-> f32 helpers (RNE pack; exact unpack)
__device__ __forceinline__ unsigned short f2bf(float f) {
    union { float f; unsigned int u; } v; v.f = f;
    unsigned int r = (v.u + 0x7FFFu + ((v.u >> 16) & 1u)) >> 16;
    return (unsigned short)r;
}
__device__ __forceinline__ float bf2f(unsigned short u) {
    union { unsigned int u; float f; } v; v.u = ((unsigned int)u) << 16;
    return v.f;
}
// unpack packed pair (low ushort = even feature, high = odd)
__device__ __forceinline__ float bflo(unsigned int u) {
    union { unsigned int u; float f; } v; v.u = u << 16;
    return v.f;
}
__device__ __forceinline__ float bfhi(unsigned int u) {
    union { unsigned int u; float f; } v; v.u = u & 0xFFFF0000u;
    return v.f;
}

// ---------------- FUSED single-pass partition (replaces p1a + 3 scans + p1c) ----------------
// Buckets get fixed padded regions of MAXB slots; each block reserves its sub-range
// with ONE atomicAdd per bucket per side (bucket-granular: ~392/block, cheap —
// round-2's disaster was PER-EDGE random atomics). Within-bucket order is
// nondeterministic, which is fine: p2s2 re-sorts by node and sums are commutative.
// dst entry: ((d&511)<<SRC_BITS)|s ; src entry: s|(bucket<<SRC_BITS) (S2 reads &511).
__global__ __launch_bounds__(256) void part_kernel(const int* __restrict__ src, const int* __restrict__ dst,
                                                   int* __restrict__ cnt,    // [2*nbuk] cursors (pre-zeroed)
                                                   int* __restrict__ pedge,  // [2*nbuk*MAXB]
                                                   int E, int nbuk) {
    __shared__ int hd[2][NBUK_MAX], hs[2][NBUK_MAX];
    __shared__ int curD[NBUK_MAX], curS[NBUK_MAX];
    __shared__ int baseD[NBUK_MAX], baseS[NBUK_MAX];
    __shared__ int stD[CH];
    __shared__ int stS[CH];
    __shared__ unsigned char bkD[CH];
    const int t = threadIdx.x;
    const int par = (t >> 6) & 1;   // wave parity halves LDS-atomic contention
    if (t < nbuk) { hd[0][t] = 0; hd[1][t] = 0; hs[0][t] = 0; hs[1][t] = 0; }
    __syncthreads();
    const int base = blockIdx.x * CH;
    const int cntE = min(CH, E - base);
    int dl[CH / 256], sl[CH / 256];
#pragma unroll
    for (int k = 0; k < CH / 256; ++k) {
        int i = t + k * 256;
        if (i < cntE) {
            dl[k] = dst[base + i];
            sl[k] = src[base + i];
            atomicAdd(&hd[par][dl[k] >> 9], 1);
            atomicAdd(&hs[par][sl[k] >> 9], 1);
        }
    }
    __syncthreads();
    int cD = 0, cS = 0;
    if (t < nbuk) {
        cD = hd[0][t] + hd[1][t];
        cS = hs[0][t] + hs[1][t];
        hd[0][t] = cD;
        hs[0][t] = cS;
    }
    __syncthreads();
    for (int off = 1; off < nbuk; off <<= 1) {
        int v0 = (t >= off && t < nbuk) ? hd[0][t - off] : 0;
        int w0 = (t >= off && t < nbuk) ? hs[0][t - off] : 0;
        __syncthreads();
        if (t < nbuk) { hd[0][t] += v0; hs[0][t] += w0; }
        __syncthreads();
    }
    if (t < nbuk) {
        int excD = hd[0][t] - cD;
        int excS = hs[0][t] - cS;
        curD[t] = excD;
        curS[t] = excS;
        int gD = atomicAdd(&cnt[t], cD);          // reserve [gD, gD+cD) in bucket t (dst)
        int gS = atomicAdd(&cnt[nbuk + t], cS);   // reserve in bucket t (src)
        baseD[t] = t * MAXB + gD - excD;
        baseS[t] = (nbuk + t) * MAXB + gS - excS;
    }
    __syncthreads();
#pragma unroll
    for (int k = 0; k < CH / 256; ++k) {
        int i = t + k * 256;
        if (i < cntE) {
            int j = dl[k] >> 9;
            int p = atomicAdd(&curD[j], 1);
            stD[p] = ((dl[k] & 511) << SRC_BITS) | sl[k];
            bkD[p] = (unsigned char)j;
            int jq = sl[k] >> 9;
            int q = atomicAdd(&curS[jq], 1);
            stS[q] = sl[k] | (jq << SRC_BITS);
        }
    }
    __syncthreads();
    for (int i = t; i < cntE; i += 256) {
        pedge[baseD[bkD[i]] + i] = stD[i];
        int v = stS[i];
        pedge[baseS[v >> SRC_BITS] + i] = v;
    }
}

// ---------------- P2+S2 merged: per-bucket sort / histograms ----------------
// blocks [0, nbuk)       : P2 role — local sort -> esrc, segS/segE, norm_dst
// blocks [nbuk, 2*nbuk)  : S2 role — src histogram -> norm_src
// Bucket b's edges live at [b*MAXB, b*MAXB + cnt[b]) (padded regions).
__global__ __launch_bounds__(512) void p2s2_kernel(const int* __restrict__ pedge,
                                                   const int* __restrict__ cnt,
                                                   int* __restrict__ esrc,
                                                   int* __restrict__ segS, int* __restrict__ segE,
                                                   float* __restrict__ norm_dst,
                                                   float* __restrict__ norm_src,
                                                   int N, int nbuk) {
    __shared__ int h[512];
    __shared__ int cur[512];
    __shared__ int stage[MAXB];
    const int t = threadIdx.x;
    const int b0 = blockIdx.x;
    if (b0 >= nbuk) {
        // ---- S2 role ----
        const int b = b0 - nbuk;
        h[t] = 0;
        __syncthreads();
        const int sb0 = (nbuk + b) * MAXB;
        const int sb1 = sb0 + cnt[nbuk + b];
        for (int i = sb0 + t; i < sb1; i += 512) atomicAdd(&h[pedge[i] & 511], 1);
        __syncthreads();
        int n = (b << 9) + t;
        if (n < N) norm_src[n] = rsqrtf(fmaxf((float)h[t], 1.0f));
        return;
    }
    // ---- P2 role ----
    const int b = b0;
    h[t] = 0;
    __syncthreads();
    const int bb0 = b * MAXB;
    const int cntHere = cnt[b];
    const int bb1 = bb0 + cntHere;
    for (int i = bb0 + t; i < bb1; i += 512) atomicAdd(&h[(pedge[i] >> SRC_BITS) & 511], 1);
    __syncthreads();
    for (int off = 1; off < 512; off <<= 1) {
        int v = (t >= off) ? h[t - off] : 0;
        __syncthreads();
        h[t] += v;
        __syncthreads();
    }
    {
        int exc = t ? h[t - 1] : 0;
        cur[t] = exc;
        int n = (b << 9) + t;
        if (n < N) {
            segS[n] = bb0 + exc;
            segE[n] = bb0 + h[t];
            norm_dst[n] = rsqrtf(fmaxf((float)(h[t] - exc), 1.0f));
        }
    }
    __syncthreads();
    for (int i = bb0 + t; i < bb1; i += 512) {
        int v = pedge[i];
        int j = (v >> SRC_BITS) & 511;
        int p = atomicAdd(&cur[j], 1);
        stage[p] = v & ((1 << SRC_BITS) - 1);   // p < cntHere <= MAXB
    }
    __syncthreads();
    for (int i = t; i < cntHere; i += 512) esrc[bb0 + i] = stage[i];
}

// ---------------- X(bf16) = (H @ W) * norm_row  — MFMA split-bf16 ----------------
// Row-major X (128 B/row = one cache line: 8 feature-lanes coalesce to ONE line
// per edge in segsum — round-4 lesson: chunk-split layouts 8x the request count).
// Row N (one past the real nodes) is all-zero: segsum's masked slots redirect to it.
template<int K>
__global__ __launch_bounds__(256) void gemm_norm(const float* __restrict__ H,
                                                 const float* __restrict__ W,
                                                 const float* __restrict__ norm,
                                                 unsigned short* __restrict__ X, int N) {
    constexpr int KP = K + 8;  // padded stride (halves)
    __shared__ __align__(16) unsigned short sHi[64 * KP];
    __shared__ __align__(16) unsigned short sLo[64 * KP];
    const int tid = threadIdx.x;

    // stage W (row-major [K][64]) transposed, split hi/lo
    for (int idx = tid; idx < K * 64; idx += 256) {
        int k = idx >> 6;
        int c = idx & 63;
        float v = W[idx];
        unsigned short hi = f2bf(v);
        sHi[c * KP + k] = hi;
        sLo[c * KP + k] = f2bf(v - bf2f(hi));
    }
    __syncthreads();

    const int w = tid >> 6;
    const int lane = tid & 63;
    const int quad = lane >> 4;
    const int l16 = lane & 15;
    const int n0 = blockIdx.x * 64;
    const int arow = n0 + w * 16 + l16;
    const int arow_c = (arow < N) ? arow : (N - 1);
    const float* Hrow = H + (size_t)arow_c * K + quad * 8;

    f32x4 acc[4];
#pragma unroll
    for (int t = 0; t < 4; ++t) acc[t] = (f32x4){0.0f, 0.0f, 0.0f, 0.0f};

    float4 p0 = *(const float4*)(Hrow + 0);
    float4 p1 = *(const float4*)(Hrow + 4);

#pragma unroll
    for (int kc = 0; kc < K / 32; ++kc) {
        const float v[8] = {p0.x, p0.y, p0.z, p0.w, p1.x, p1.y, p1.z, p1.w};
        bf16x8 aHi, aLo;
#pragma unroll
        for (int j = 0; j < 8; ++j) {
            unsigned short hi = f2bf(v[j]);
            aHi[j] = (short)hi;
            aLo[j] = (short)f2bf(v[j] - bf2f(hi));
        }
        if (kc + 1 < K / 32) {
            p0 = *(const float4*)(Hrow + (kc + 1) * 32 + 0);
            p1 = *(const float4*)(Hrow + (kc + 1) * 32 + 4);
        }
        const int kbase = kc * 32 + quad * 8;
#pragma unroll
        for (int t = 0; t < 4; ++t) {
            const int col = t * 16 + l16;
            const bf16x8 bHi = *(const bf16x8*)&sHi[col * KP + kbase];
            const bf16x8 bLo = *(const bf16x8*)&sLo[col * KP + kbase];
            acc[t] = __builtin_amdgcn_mfma_f32_16x16x32_bf16(aLo, bHi, acc[t], 0, 0, 0);
            acc[t] = __builtin_amdgcn_mfma_f32_16x16x32_bf16(aHi, bLo, acc[t], 0, 0, 0);
            acc[t] = __builtin_amdgcn_mfma_f32_16x16x32_bf16(aHi, bHi, acc[t], 0, 0, 0);
        }
    }

#pragma unroll
    for (int r = 0; r < 4; ++r) {
        const int node = n0 + w * 16 + quad * 4 + r;
        if (node < N) {
            const float s = norm[node];
#pragma unroll
            for (int t = 0; t < 4; ++t) {
                X[(size_t)node * 64 + t * 16 + l16] = f2bf(acc[t][r] * s);
            }
        } else if (node == N) {
            // zero row for segsum's masked-slot redirect
#pragma unroll
            for (int t = 0; t < 4; ++t) {
                X[(size_t)node * 64 + t * 16 + l16] = 0;
            }
        }
    }
}

// ---------------- segment sum over CSR (bf16 X rows) + fused epilogue ----------------
// 1 node per wave (zero divergence). FLAT-32 with VECTOR esrc read: slot eh owns
// 4 consecutive edges loaded as one uint4 (dwordx4) -> 1 index load + 4 independent
// masked-redirect row gathers per pass. deg ~ Poisson(16): one pass covers ~all nodes.
// Out-of-range slots gather the L1-hot zero row X[N].
// Epilogue: 3-stage reduce-scatter -> each lane owns one feature -> coalesced store.
template<bool ELU>
__global__ __launch_bounds__(256) void segsum_kernel(const unsigned short* __restrict__ X,
                                                     const int* __restrict__ esrc,
                                                     const int* __restrict__ segS,
                                                     const int* __restrict__ segE,
                                                     const float* __restrict__ norm_dst,
                                                     const float* __restrict__ bias,
                                                     float* __restrict__ out, int N) {
    const int node = __builtin_amdgcn_readfirstlane(blockIdx.x * 4 + (threadIdx.x >> 6));
    if (node >= N) return;
    const int lane = threadIdx.x & 63;
    const int eh = lane >> 3;          // edge slot 0..7 (owns 4 consecutive edges)
    const int fl = lane & 7;           // feature group (8 bf16 = 16 B)
    const unsigned flo = (unsigned)fl << 4;
    // feature this lane will own after reduce-scatter (bit-reversed eh)
    const int fown = fl * 8 + ((eh & 1) << 2) + (eh & 2) + (eh >> 2);
    const float bv = bias[fown];
    const int s0 = segS[node];
    const int s1 = segE[node];
    const char* Xb = (const char*)X;
    f32x2 A0 = {0.0f, 0.0f}, A1 = {0.0f, 0.0f}, A2 = {0.0f, 0.0f}, A3 = {0.0f, 0.0f};
#define ACC8(u) \
    A0 += (f32x2){bflo(u.x), bfhi(u.x)}; A1 += (f32x2){bflo(u.y), bfhi(u.y)}; \
    A2 += (f32x2){bflo(u.z), bfhi(u.z)}; A3 += (f32x2){bflo(u.w), bfhi(u.w)};
    int e = s0;
    while (true) {
        const int b4 = e + eh * 4;
        const uint4 q = *(const uint4*)&esrc[b4];   // 4B-aligned dwordx4; esrc padded
        const int r0 = (b4 + 0 < s1) ? (int)q.x : N;
        const int r1 = (b4 + 1 < s1) ? (int)q.y : N;
        const int r2 = (b4 + 2 < s1) ? (int)q.z : N;
        const int r3 = (b4 + 3 < s1) ? (int)q.w : N;
        const uint4 u0 = *(const uint4*)(Xb + ((((unsigned)r0) << 7) | flo));
        const uint4 u1 = *(const uint4*)(Xb + ((((unsigned)r1) << 7) | flo));
        const uint4 u2 = *(const uint4*)(Xb + ((((unsigned)r2) << 7) | flo));
        const uint4 u3 = *(const uint4*)(Xb + ((((unsigned)r3) << 7) | flo));
        ACC8(u0);
        ACC8(u1);
        ACC8(u2);
        ACC8(u3);
        e += 32;
        if (e >= s1) break;
    }
#undef ACC8
    // reduce-scatter across the 8 slots: 3 stages, each lane keeps a shrinking set
    float a0 = A0.x, a1 = A0.y, a2 = A1.x, a3 = A1.y;
    float a4 = A2.x, a5 = A2.y, a6 = A3.x, a7 = A3.y;
    const bool p0 = (eh & 1) != 0;
    const bool p1 = (eh & 2) != 0;
    const bool p2 = (eh & 4) != 0;
    float t0, t1, t2, t3;
    {
        float sA = p0 ? a0 : a4, kA = p0 ? a4 : a0;
        float sB = p0 ? a1 : a5, kB = p0 ? a5 : a1;
        float sC = p0 ? a2 : a6, kC = p0 ? a6 : a2;
        float sD = p0 ? a3 : a7, kD = p0 ? a7 : a3;
        t0 = kA + __shfl_xor(sA, 8);
        t1 = kB + __shfl_xor(sB, 8);
        t2 = kC + __shfl_xor(sC, 8);
        t3 = kD + __shfl_xor(sD, 8);
    }
    float u0, u1;
    {
        float sA = p1 ? t0 : t2, kA = p1 ? t2 : t0;
        float sB = p1 ? t1 : t3, kB = p1 ? t3 : t1;
        u0 = kA + __shfl_xor(sA, 16);
        u1 = kB + __shfl_xor(sB, 16);
    }
    float v;
    {
        float sA = p2 ? u0 : u1, kA = p2 ? u1 : u0;
        v = kA + __shfl_xor(sA, 32);
    }
    // epilogue: every lane handles exactly one feature
    const float s = norm_dst[node];
    float r = v * s + bv;
    if (ELU) r = r > 0.0f ? r : expm1f(r);
    out[(size_t)node * 64 + fown] = r;
}

extern "C" void kernel_launch(void* const* d_in, const int* in_sizes, int n_in,
                              void* d_out, int out_size, void* d_ws, size_t ws_size,
                              hipStream_t stream) {
    const float* h   = (const float*)d_in[0];
    const int*   src = (const int*)d_in[1];
    const int*   dst = (const int*)d_in[2];
    const float* W1  = (const float*)d_in[3];
    const float* b1  = (const float*)d_in[4];
    const float* W2  = (const float*)d_in[5];
    const float* b2  = (const float*)d_in[6];
    float* out = (float*)d_out;

    const int N = in_sizes[0] / 128;       // 100000
    const int E = in_sizes[1];             // 1600000
    const int nbuk = (N + 511) >> 9;       // 196
    const int B1 = (E + CH - 1) / CH;      // 391

    int* iw = (int*)d_ws;
    int* cnt   = iw;                                   // 2*nbuk cursors
    int* pedge = cnt + 2 * nbuk;                       // 2*nbuk*MAXB (padded bucket regions)
    int* esrc  = pedge + 2 * (size_t)nbuk * MAXB;      // nbuk*MAXB (+40 pad for over-read)
    int* segS  = esrc + (size_t)nbuk * MAXB + 40;      // N
    int* segE  = segS + (size_t)N;                     // N
    uintptr_t fp = (uintptr_t)(segE + (size_t)N);
    fp = (fp + 63) & ~(uintptr_t)63;
    float* norm_src = (float*)fp;                      // N
    float* norm_dst = norm_src + (size_t)N;            // N
    float* H1       = norm_dst + (size_t)N;            // 64N floats
    unsigned short* Xb = (unsigned short*)(H1 + 64 * (size_t)N);  // 64(N+1) bf16

    // ---- CSR build (single-pass partition) ----
    hipMemsetAsync(cnt, 0, 2 * nbuk * sizeof(int), stream);
    part_kernel<<<B1, 256, 0, stream>>>(src, dst, cnt, pedge, E, nbuk);
    p2s2_kernel<<<2 * nbuk, 512, 0, stream>>>(pedge, cnt, esrc, segS, segE,
                                              norm_dst, norm_src, N, nbuk);

    const int segGrid = (N + 3) / 4;
    const int gemmGrid = (N + 64) / 64;    // +1 so the zero row (node==N) is always written

    // ---- layer 1 ----
    gemm_norm<128><<<gemmGrid, 256, 0, stream>>>(h, W1, norm_src, Xb, N);
    segsum_kernel<true><<<segGrid, 256, 0, stream>>>(Xb, esrc, segS, segE, norm_dst, b1, H1, N);

    // ---- layer 2 ----
    gemm_norm<64><<<gemmGrid, 256, 0, stream>>>(H1, W2, norm_src, Xb, N);
    segsum_kernel<false><<<segGrid, 256, 0, stream>>>(Xb, esrc, segS, segE, norm_dst, b2, out, N);
}

// Round 8
// 238.933 us; speedup vs baseline: 1.1066x; 1.1066x over previous
//
#include <hip/hip_runtime.h>
#include <math.h>

#define CH 4096        // edges per partition block
#define NBUK_MAX 256   // max buckets (N <= 131072)
#define MAXB 12288     // max edges per bucket staged in LDS (48 KB)
#define SRC_BITS 17    // N < 131072 fits in 17 bits

typedef short bf16x8 __attribute__((ext_vector_type(8)));
typedef float f32x4 __attribute__((ext_vector_type(4)));
typedef float f32x2 __attribute__((ext_vector_type(2)));

// bf16 <-> f32 helpers (RNE pack; exact unpack)
__device__ __forceinline__ unsigned short f2bf(float f) {
    union { float f; unsigned int u; } v; v.f = f;
    unsigned int r = (v.u + 0x7FFFu + ((v.u >> 16) & 1u)) >> 16;
    return (unsigned short)r;
}
__device__ __forceinline__ float bf2f(unsigned short u) {
    union { unsigned int u; float f; } v; v.u = ((unsigned int)u) << 16;
    return v.f;
}
// unpack packed pair (low ushort = even feature, high = odd)
__device__ __forceinline__ float bflo(unsigned int u) {
    union { unsigned int u; float f; } v; v.u = u << 16;
    return v.f;
}
__device__ __forceinline__ float bfhi(unsigned int u) {
    union { unsigned int u; float f; } v; v.u = u & 0xFFFF0000u;
    return v.f;
}

// ---------------- P1a: per-block bucket histograms (dst + src, LDS only) ----------------
// Round-2 lesson: NO global atomicAdd(&deg[src],1) (32 B write-through per op, 68 us).
// Round-7 lesson: the fused one-pass partition (bucket-region reservation via global
// atomics, no scan) REGRESSED +25.7 us total — this separated pipeline is the
// measured optimum (238.7 us). Wave-parity dual sub-histograms halve LDS contention.
__global__ __launch_bounds__(256) void p1a_kernel(const int* __restrict__ src, const int* __restrict__ dst,
                                                  int* __restrict__ mat, int E, int B1, int nbuk) {
    __shared__ int hd[2][NBUK_MAX], hs[2][NBUK_MAX];
    const int t = threadIdx.x;
    const int p = (t >> 6) & 1;   // wave parity
    if (t < nbuk) { hd[0][t] = 0; hd[1][t] = 0; hs[0][t] = 0; hs[1][t] = 0; }
    __syncthreads();
    const int base = blockIdx.x * CH;
    const int cnt = min(CH, E - base);
    for (int k = t; k < cnt; k += 256) {
        int d = dst[base + k];
        int s = src[base + k];
        atomicAdd(&hd[p][d >> 9], 1);
        atomicAdd(&hs[p][s >> 9], 1);
    }
    __syncthreads();
    if (t < nbuk) {
        mat[t * B1 + blockIdx.x] = hd[0][t] + hd[1][t];
        mat[(nbuk + t) * B1 + blockIdx.x] = hs[0][t] + hs[1][t];
    }
}

// ---------------- 3-phase exclusive scan ----------------
__global__ __launch_bounds__(256) void scan1_kernel(const int* __restrict__ cnt,
                                                    int* __restrict__ seg,
                                                    int* __restrict__ bsums, int N) {
    __shared__ int tsum[256];
    const int t = threadIdx.x;
    const int base = blockIdx.x * 1024 + t * 4;
    int v0 = (base + 0 < N) ? cnt[base + 0] : 0;
    int v1 = (base + 1 < N) ? cnt[base + 1] : 0;
    int v2 = (base + 2 < N) ? cnt[base + 2] : 0;
    int v3 = (base + 3 < N) ? cnt[base + 3] : 0;
    tsum[t] = v0 + v1 + v2 + v3;
    __syncthreads();
    for (int off = 1; off < 256; off <<= 1) {
        int x = (t >= off) ? tsum[t - off] : 0;
        __syncthreads();
        if (t >= off) tsum[t] += x;
        __syncthreads();
    }
    int run = (t > 0) ? tsum[t - 1] : 0;
    if (base + 0 < N) seg[base + 0] = run; run += v0;
    if (base + 1 < N) seg[base + 1] = run; run += v1;
    if (base + 2 < N) seg[base + 2] = run; run += v2;
    if (base + 3 < N) seg[base + 3] = run;
    if (t == 255) bsums[blockIdx.x] = tsum[255];
}

__global__ void scan2_kernel(int* __restrict__ bsums, int* __restrict__ seg, int N, int G) {
    __shared__ int s[256];
    int t = threadIdx.x;
    if (t < G) s[t] = bsums[t];
    __syncthreads();
    if (t == 0) {
        int run = 0;
        for (int i = 0; i < G; ++i) { int v = s[i]; s[i] = run; run += v; }
        seg[N] = run;
    }
    __syncthreads();
    if (t < G) bsums[t] = s[t];
}

__global__ __launch_bounds__(256) void scan3_kernel(int* __restrict__ seg,
                                                    const int* __restrict__ bsums, int N) {
    int add = bsums[blockIdx.x];
    int base = blockIdx.x * 1024 + threadIdx.x * 4;
#pragma unroll
    for (int i = 0; i < 4; ++i) {
        int idx = base + i;
        if (idx < N) seg[idx] += add;
    }
}

// ---------------- P1c: LDS-staged partition scatter (both sides) ----------------
// Bucket id recorded at scatter time (bkD uchar for dst side; packed into the
// free high bits of stS for src side) -> writeout has ZERO binary searches.
// Downstream: P2 reads dst entries with (v>>SRC_BITS)&511 and v&0x1FFFF; S2 reads
// src entries with &511 -- the packed bucket bits are invisible to both.
__global__ __launch_bounds__(256) void p1c_kernel(const int* __restrict__ src, const int* __restrict__ dst,
                                                  const int* __restrict__ mat,
                                                  const int* __restrict__ scan,
                                                  int* __restrict__ pedge,
                                                  int E, int B1, int nbuk) {
    __shared__ int hd[NBUK_MAX], hs[NBUK_MAX];
    __shared__ int curD[NBUK_MAX], curS[NBUK_MAX];
    __shared__ int baseD[NBUK_MAX], baseS[NBUK_MAX];
    __shared__ int stD[CH];
    __shared__ int stS[CH];
    __shared__ unsigned char bkD[CH];
    const int t = threadIdx.x;
    if (t < nbuk) {
        hd[t] = mat[t * B1 + blockIdx.x];
        hs[t] = mat[(nbuk + t) * B1 + blockIdx.x];
    }
    const int base = blockIdx.x * CH;
    const int cnt = min(CH, E - base);
    int dl[CH / 256], sl[CH / 256];
#pragma unroll
    for (int k = 0; k < CH / 256; ++k) {
        int i = t + k * 256;
        if (i < cnt) {
            dl[k] = dst[base + i];
            sl[k] = src[base + i];
        }
    }
    __syncthreads();
    for (int off = 1; off < nbuk; off <<= 1) {
        int v0 = (t >= off && t < nbuk) ? hd[t - off] : 0;
        int w0 = (t >= off && t < nbuk) ? hs[t - off] : 0;
        __syncthreads();
        if (t < nbuk) { hd[t] += v0; hs[t] += w0; }
        __syncthreads();
    }
    if (t < nbuk) {
        int excD = t ? hd[t - 1] : 0;
        int excS = t ? hs[t - 1] : 0;
        curD[t] = excD;
        curS[t] = excS;
        baseD[t] = scan[t * B1 + blockIdx.x] - excD;
        baseS[t] = scan[(nbuk + t) * B1 + blockIdx.x] - excS;
    }
    __syncthreads();
#pragma unroll
    for (int k = 0; k < CH / 256; ++k) {
        int i = t + k * 256;
        if (i < cnt) {
            int j = dl[k] >> 9;
            int p = atomicAdd(&curD[j], 1);
            stD[p] = ((dl[k] & 511) << SRC_BITS) | sl[k];
            bkD[p] = (unsigned char)j;
            int jq = sl[k] >> 9;
            int q = atomicAdd(&curS[jq], 1);
            stS[q] = sl[k] | (jq << SRC_BITS);
        }
    }
    __syncthreads();
    for (int i = t; i < cnt; i += 256) {
        int b = bkD[i];
        pedge[baseD[b] + i] = stD[i];
        int v = stS[i];
        pedge[baseS[v >> SRC_BITS] + i] = v;
    }
}

// ---------------- P2+S2 merged: per-bucket sort / histograms ----------------
// blocks [0, nbuk)       : P2 role — local sort -> esrc, seg, norm_dst
// blocks [nbuk, 2*nbuk)  : S2 role — src histogram -> norm_src
__global__ __launch_bounds__(512) void p2s2_kernel(const int* __restrict__ pedge,
                                                   const int* __restrict__ scan,
                                                   int* __restrict__ esrc, int* __restrict__ seg,
                                                   float* __restrict__ norm_dst,
                                                   float* __restrict__ norm_src,
                                                   int N, int E, int B1, int nbuk) {
    __shared__ int h[512];
    __shared__ int cur[512];
    __shared__ int stage[MAXB];
    const int t = threadIdx.x;
    const int b0 = blockIdx.x;
    if (b0 >= nbuk) {
        // ---- S2 role ----
        const int b = b0 - nbuk;
        h[t] = 0;
        __syncthreads();
        const int sb0 = scan[(nbuk + b) * B1];
        const int sb1 = scan[(nbuk + b + 1) * B1];
        for (int i = sb0 + t; i < sb1; i += 512) atomicAdd(&h[pedge[i] & 511], 1);
        __syncthreads();
        int n = (b << 9) + t;
        if (n < N) norm_src[n] = rsqrtf(fmaxf((float)h[t], 1.0f));
        return;
    }
    // ---- P2 role ----
    const int b = b0;
    h[t] = 0;
    __syncthreads();
    const int bb0 = scan[b * B1];
    const int bb1 = scan[(b + 1) * B1];
    for (int i = bb0 + t; i < bb1; i += 512) atomicAdd(&h[(pedge[i] >> SRC_BITS) & 511], 1);
    __syncthreads();
    for (int off = 1; off < 512; off <<= 1) {
        int v = (t >= off) ? h[t - off] : 0;
        __syncthreads();
        h[t] += v;
        __syncthreads();
    }
    {
        int exc = t ? h[t - 1] : 0;
        cur[t] = exc;
        int n = (b << 9) + t;
        if (n < N) {
            seg[n] = bb0 + exc;
            norm_dst[n] = rsqrtf(fmaxf((float)(h[t] - exc), 1.0f));
        }
        if (b == 0 && t == 0) seg[N] = E;
    }
    __syncthreads();
    const int cnt = bb1 - bb0;
    for (int i = bb0 + t; i < bb1; i += 512) {
        int v = pedge[i];
        int j = (v >> SRC_BITS) & 511;
        int p = atomicAdd(&cur[j], 1);
        int s = v & ((1 << SRC_BITS) - 1);
        if (p < MAXB) stage[p] = s; else esrc[bb0 + p] = s;
    }
    __syncthreads();
    for (int i = t; i < cnt && i < MAXB; i += 512) esrc[bb0 + i] = stage[i];
}

// ---------------- X(bf16) = (H @ W) * norm_row  — MFMA split-bf16 ----------------
// Row-major X (128 B/row = one cache line: 8 feature-lanes coalesce to ONE line
// per edge in segsum — round-4 lesson: chunk-split layouts 8x the request count).
// Row N (one past the real nodes) is all-zero: segsum's masked slots redirect to it.
template<int K>
__global__ __launch_bounds__(256) void gemm_norm(const float* __restrict__ H,
                                                 const float* __restrict__ W,
                                                 const float* __restrict__ norm,
                                                 unsigned short* __restrict__ X, int N) {
    constexpr int KP = K + 8;  // padded stride (halves)
    __shared__ __align__(16) unsigned short sHi[64 * KP];
    __shared__ __align__(16) unsigned short sLo[64 * KP];
    const int tid = threadIdx.x;

    // stage W (row-major [K][64]) transposed, split hi/lo
    for (int idx = tid; idx < K * 64; idx += 256) {
        int k = idx >> 6;
        int c = idx & 63;
        float v = W[idx];
        unsigned short hi = f2bf(v);
        sHi[c * KP + k] = hi;
        sLo[c * KP + k] = f2bf(v - bf2f(hi));
    }
    __syncthreads();

    const int w = tid >> 6;
    const int lane = tid & 63;
    const int quad = lane >> 4;
    const int l16 = lane & 15;
    const int n0 = blockIdx.x * 64;
    const int arow = n0 + w * 16 + l16;
    const int arow_c = (arow < N) ? arow : (N - 1);
    const float* Hrow = H + (size_t)arow_c * K + quad * 8;

    f32x4 acc[4];
#pragma unroll
    for (int t = 0; t < 4; ++t) acc[t] = (f32x4){0.0f, 0.0f, 0.0f, 0.0f};

    float4 p0 = *(const float4*)(Hrow + 0);
    float4 p1 = *(const float4*)(Hrow + 4);

#pragma unroll
    for (int kc = 0; kc < K / 32; ++kc) {
        const float v[8] = {p0.x, p0.y, p0.z, p0.w, p1.x, p1.y, p1.z, p1.w};
        bf16x8 aHi, aLo;
#pragma unroll
        for (int j = 0; j < 8; ++j) {
            unsigned short hi = f2bf(v[j]);
            aHi[j] = (short)hi;
            aLo[j] = (short)f2bf(v[j] - bf2f(hi));
        }
        if (kc + 1 < K / 32) {
            p0 = *(const float4*)(Hrow + (kc + 1) * 32 + 0);
            p1 = *(const float4*)(Hrow + (kc + 1) * 32 + 4);
        }
        const int kbase = kc * 32 + quad * 8;
#pragma unroll
        for (int t = 0; t < 4; ++t) {
            const int col = t * 16 + l16;
            const bf16x8 bHi = *(const bf16x8*)&sHi[col * KP + kbase];
            const bf16x8 bLo = *(const bf16x8*)&sLo[col * KP + kbase];
            acc[t] = __builtin_amdgcn_mfma_f32_16x16x32_bf16(aLo, bHi, acc[t], 0, 0, 0);
            acc[t] = __builtin_amdgcn_mfma_f32_16x16x32_bf16(aHi, bLo, acc[t], 0, 0, 0);
            acc[t] = __builtin_amdgcn_mfma_f32_16x16x32_bf16(aHi, bHi, acc[t], 0, 0, 0);
        }
    }

#pragma unroll
    for (int r = 0; r < 4; ++r) {
        const int node = n0 + w * 16 + quad * 4 + r;
        if (node < N) {
            const float s = norm[node];
#pragma unroll
            for (int t = 0; t < 4; ++t) {
                X[(size_t)node * 64 + t * 16 + l16] = f2bf(acc[t][r] * s);
            }
        } else if (node == N) {
            // zero row for segsum's masked-slot redirect
#pragma unroll
            for (int t = 0; t < 4; ++t) {
                X[(size_t)node * 64 + t * 16 + l16] = 0;
            }
        }
    }
}

// ---------------- segment sum over CSR (bf16 X rows) + fused epilogue ----------------
// 1 node per wave (zero divergence). FLAT-32 with VECTOR esrc read: slot eh owns
// 4 consecutive edges loaded as one uint4 (dwordx4) -> 1 index load + 4 independent
// masked-redirect row gathers per pass. deg ~ Poisson(16): one pass covers ~all nodes.
// Out-of-range slots gather the L1-hot zero row X[N].
// Epilogue: 3-stage reduce-scatter -> each lane owns one feature -> coalesced store.
template<bool ELU>
__global__ __launch_bounds__(256) void segsum_kernel(const unsigned short* __restrict__ X,
                                                     const int* __restrict__ esrc,
                                                     const int* __restrict__ seg,
                                                     const float* __restrict__ norm_dst,
                                                     const float* __restrict__ bias,
                                                     float* __restrict__ out, int N) {
    const int node = __builtin_amdgcn_readfirstlane(blockIdx.x * 4 + (threadIdx.x >> 6));
    if (node >= N) return;
    const int lane = threadIdx.x & 63;
    const int eh = lane >> 3;          // edge slot 0..7 (owns 4 consecutive edges)
    const int fl = lane & 7;           // feature group (8 bf16 = 16 B)
    const unsigned flo = (unsigned)fl << 4;
    // feature this lane will own after reduce-scatter (bit-reversed eh)
    const int fown = fl * 8 + ((eh & 1) << 2) + (eh & 2) + (eh >> 2);
    const float bv = bias[fown];
    const int s0 = seg[node];
    const int s1 = seg[node + 1];
    const char* Xb = (const char*)X;
    f32x2 A0 = {0.0f, 0.0f}, A1 = {0.0f, 0.0f}, A2 = {0.0f, 0.0f}, A3 = {0.0f, 0.0f};
#define ACC8(u) \
    A0 += (f32x2){bflo(u.x), bfhi(u.x)}; A1 += (f32x2){bflo(u.y), bfhi(u.y)}; \
    A2 += (f32x2){bflo(u.z), bfhi(u.z)}; A3 += (f32x2){bflo(u.w), bfhi(u.w)};
    int e = s0;
    while (true) {
        const int b4 = e + eh * 4;
        const uint4 q = *(const uint4*)&esrc[b4];   // 4B-aligned dwordx4; esrc padded
        const int r0 = (b4 + 0 < s1) ? (int)q.x : N;
        const int r1 = (b4 + 1 < s1) ? (int)q.y : N;
        const int r2 = (b4 + 2 < s1) ? (int)q.z : N;
        const int r3 = (b4 + 3 < s1) ? (int)q.w : N;
        const uint4 u0 = *(const uint4*)(Xb + ((((unsigned)r0) << 7) | flo));
        const uint4 u1 = *(const uint4*)(Xb + ((((unsigned)r1) << 7) | flo));
        const uint4 u2 = *(const uint4*)(Xb + ((((unsigned)r2) << 7) | flo));
        const uint4 u3 = *(const uint4*)(Xb + ((((unsigned)r3) << 7) | flo));
        ACC8(u0);
        ACC8(u1);
        ACC8(u2);
        ACC8(u3);
        e += 32;
        if (e >= s1) break;
    }
#undef ACC8
    // reduce-scatter across the 8 slots: 3 stages, each lane keeps a shrinking set
    float a0 = A0.x, a1 = A0.y, a2 = A1.x, a3 = A1.y;
    float a4 = A2.x, a5 = A2.y, a6 = A3.x, a7 = A3.y;
    const bool p0 = (eh & 1) != 0;
    const bool p1 = (eh & 2) != 0;
    const bool p2 = (eh & 4) != 0;
    float t0, t1, t2, t3;
    {
        float sA = p0 ? a0 : a4, kA = p0 ? a4 : a0;
        float sB = p0 ? a1 : a5, kB = p0 ? a5 : a1;
        float sC = p0 ? a2 : a6, kC = p0 ? a6 : a2;
        float sD = p0 ? a3 : a7, kD = p0 ? a7 : a3;
        t0 = kA + __shfl_xor(sA, 8);
        t1 = kB + __shfl_xor(sB, 8);
        t2 = kC + __shfl_xor(sC, 8);
        t3 = kD + __shfl_xor(sD, 8);
    }
    float u0, u1;
    {
        float sA = p1 ? t0 : t2, kA = p1 ? t2 : t0;
        float sB = p1 ? t1 : t3, kB = p1 ? t3 : t1;
        u0 = kA + __shfl_xor(sA, 16);
        u1 = kB + __shfl_xor(sB, 16);
    }
    float v;
    {
        float sA = p2 ? u0 : u1, kA = p2 ? u1 : u0;
        v = kA + __shfl_xor(sA, 32);
    }
    // epilogue: every lane handles exactly one feature
    const float s = norm_dst[node];
    float r = v * s + bv;
    if (ELU) r = r > 0.0f ? r : expm1f(r);
    out[(size_t)node * 64 + fown] = r;
}

extern "C" void kernel_launch(void* const* d_in, const int* in_sizes, int n_in,
                              void* d_out, int out_size, void* d_ws, size_t ws_size,
                              hipStream_t stream) {
    const float* h   = (const float*)d_in[0];
    const int*   src = (const int*)d_in[1];
    const int*   dst = (const int*)d_in[2];
    const float* W1  = (const float*)d_in[3];
    const float* b1  = (const float*)d_in[4];
    const float* W2  = (const float*)d_in[5];
    const float* b2  = (const float*)d_in[6];
    float* out = (float*)d_out;

    const int N = in_sizes[0] / 128;       // 100000
    const int E = in_sizes[1];             // 1600000
    const int nbuk = (N + 511) >> 9;       // 196
    const int B1 = (E + CH - 1) / CH;      // 391
    const int M = 2 * nbuk * B1;

    int* iw = (int*)d_ws;
    int* mat   = iw;                       // M
    int* scanb = mat + M;                  // M+4
    int* bsums = scanb + M + 4;            // 256
    int* pedge = bsums + 256;              // 2E
    int* esrc  = pedge + 2 * (size_t)E;    // E (+40 pad for flat-32 over-read)
    int* seg   = esrc + (size_t)E + 40;    // N+1 (+pad)
    uintptr_t fp = (uintptr_t)(seg + (size_t)N + 4);
    fp = (fp + 63) & ~(uintptr_t)63;
    float* norm_src = (float*)fp;                      // N
    float* norm_dst = norm_src + (size_t)N;            // N
    float* H1       = norm_dst + (size_t)N;            // 64N floats
    unsigned short* Xb = (unsigned short*)(H1 + 64 * (size_t)N);  // 64(N+1) bf16

    // ---- CSR build ----
    p1a_kernel<<<B1, 256, 0, stream>>>(src, dst, mat, E, B1, nbuk);
    const int G = (M + 1023) / 1024;
    scan1_kernel<<<G, 256, 0, stream>>>(mat, scanb, bsums, M);
    scan2_kernel<<<1, 256, 0, stream>>>(bsums, scanb, M, G);
    scan3_kernel<<<G, 256, 0, stream>>>(scanb, bsums, M);
    p1c_kernel<<<B1, 256, 0, stream>>>(src, dst, mat, scanb, pedge, E, B1, nbuk);
    p2s2_kernel<<<2 * nbuk, 512, 0, stream>>>(pedge, scanb, esrc, seg, norm_dst, norm_src,
                                              N, E, B1, nbuk);

    const int segGrid = (N + 3) / 4;
    const int gemmGrid = (N + 64) / 64;    // +1 so the zero row (node==N) is always written

    // ---- layer 1 ----
    gemm_norm<128><<<gemmGrid, 256, 0, stream>>>(h, W1, norm_src, Xb, N);
    segsum_kernel<true><<<segGrid, 256, 0, stream>>>(Xb, esrc, seg, norm_dst, b1, H1, N);

    // ---- layer 2 ----
    gemm_norm<64><<<gemmGrid, 256, 0, stream>>>(H1, W2, norm_src, Xb, N);
    segsum_kernel<false><<<segGrid, 256, 0, stream>>>(Xb, esrc, seg, norm_dst, b2, out, N);
}

// Round 10
// 236.650 us; speedup vs baseline: 1.1173x; 1.0096x over previous
//
#include <hip/hip_runtime.h>
#include <math.h>

#define CH 4096        // edges per partition block
#define NBUK_MAX 256   // max buckets (N <= 131072)
#define MAXB 12288     // max edges per bucket staged in LDS (48 KB)
#define SRC_BITS 17    // N < 131072 fits in 17 bits

typedef short bf16x8 __attribute__((ext_vector_type(8)));
typedef float f32x4 __attribute__((ext_vector_type(4)));
typedef float f32x2 __attribute__((ext_vector_type(2)));

// bf16 <-> f32 helpers (RNE pack; exact unpack)
__device__ __forceinline__ unsigned short f2bf(float f) {
    union { float f; unsigned int u; } v; v.f = f;
    unsigned int r = (v.u + 0x7FFFu + ((v.u >> 16) & 1u)) >> 16;
    return (unsigned short)r;
}
__device__ __forceinline__ float bf2f(unsigned short u) {
    union { unsigned int u; float f; } v; v.u = ((unsigned int)u) << 16;
    return v.f;
}
// unpack packed pair (low ushort = even feature, high = odd)
__device__ __forceinline__ float bflo(unsigned int u) {
    union { unsigned int u; float f; } v; v.u = u << 16;
    return v.f;
}
__device__ __forceinline__ float bfhi(unsigned int u) {
    union { unsigned int u; float f; } v; v.u = u & 0xFFFF0000u;
    return v.f;
}

// ---------------- P1a: per-block bucket histograms (dst + src, LDS only) ----------------
// Round-2 lesson: NO global atomicAdd(&deg[src],1). Round-7 lesson: keep the
// separated scan pipeline. Round-9: int4-vectorized staging loads — p1a runs at
// only ~1.5 waves/SIMD (391 blocks), so per-thread MLP is the only latency hiding;
// 8 independent 16 B loads per thread replace 32 serial scalar loads.
__global__ __launch_bounds__(256) void p1a_kernel(const int* __restrict__ src, const int* __restrict__ dst,
                                                  int* __restrict__ mat, int E, int B1, int nbuk) {
    __shared__ int hd[2][NBUK_MAX], hs[2][NBUK_MAX];
    const int t = threadIdx.x;
    const int p = (t >> 6) & 1;   // wave parity
    if (t < nbuk) { hd[0][t] = 0; hd[1][t] = 0; hs[0][t] = 0; hs[1][t] = 0; }
    __syncthreads();
    const int base = blockIdx.x * CH;
    const int cnt = min(CH, E - base);
    if (cnt == CH) {
        const int4* S4 = (const int4*)(src + base);
        const int4* D4 = (const int4*)(dst + base);
        int4 d0 = D4[t], d1 = D4[t + 256], d2 = D4[t + 512], d3 = D4[t + 768];
        int4 s0 = S4[t], s1 = S4[t + 256], s2 = S4[t + 512], s3 = S4[t + 768];
        atomicAdd(&hd[p][d0.x >> 9], 1); atomicAdd(&hd[p][d0.y >> 9], 1);
        atomicAdd(&hd[p][d0.z >> 9], 1); atomicAdd(&hd[p][d0.w >> 9], 1);
        atomicAdd(&hd[p][d1.x >> 9], 1); atomicAdd(&hd[p][d1.y >> 9], 1);
        atomicAdd(&hd[p][d1.z >> 9], 1); atomicAdd(&hd[p][d1.w >> 9], 1);
        atomicAdd(&hd[p][d2.x >> 9], 1); atomicAdd(&hd[p][d2.y >> 9], 1);
        atomicAdd(&hd[p][d2.z >> 9], 1); atomicAdd(&hd[p][d2.w >> 9], 1);
        atomicAdd(&hd[p][d3.x >> 9], 1); atomicAdd(&hd[p][d3.y >> 9], 1);
        atomicAdd(&hd[p][d3.z >> 9], 1); atomicAdd(&hd[p][d3.w >> 9], 1);
        atomicAdd(&hs[p][s0.x >> 9], 1); atomicAdd(&hs[p][s0.y >> 9], 1);
        atomicAdd(&hs[p][s0.z >> 9], 1); atomicAdd(&hs[p][s0.w >> 9], 1);
        atomicAdd(&hs[p][s1.x >> 9], 1); atomicAdd(&hs[p][s1.y >> 9], 1);
        atomicAdd(&hs[p][s1.z >> 9], 1); atomicAdd(&hs[p][s1.w >> 9], 1);
        atomicAdd(&hs[p][s2.x >> 9], 1); atomicAdd(&hs[p][s2.y >> 9], 1);
        atomicAdd(&hs[p][s2.z >> 9], 1); atomicAdd(&hs[p][s2.w >> 9], 1);
        atomicAdd(&hs[p][s3.x >> 9], 1); atomicAdd(&hs[p][s3.y >> 9], 1);
        atomicAdd(&hs[p][s3.z >> 9], 1); atomicAdd(&hs[p][s3.w >> 9], 1);
    } else {
        for (int k = t; k < cnt; k += 256) {
            int d = dst[base + k];
            int s = src[base + k];
            atomicAdd(&hd[p][d >> 9], 1);
            atomicAdd(&hs[p][s >> 9], 1);
        }
    }
    __syncthreads();
    if (t < nbuk) {
        mat[t * B1 + blockIdx.x] = hd[0][t] + hd[1][t];
        mat[(nbuk + t) * B1 + blockIdx.x] = hs[0][t] + hs[1][t];
    }
}

// ---------------- 3-phase exclusive scan ----------------
__global__ __launch_bounds__(256) void scan1_kernel(const int* __restrict__ cnt,
                                                    int* __restrict__ seg,
                                                    int* __restrict__ bsums, int N) {
    __shared__ int tsum[256];
    const int t = threadIdx.x;
    const int base = blockIdx.x * 1024 + t * 4;
    int v0 = (base + 0 < N) ? cnt[base + 0] : 0;
    int v1 = (base + 1 < N) ? cnt[base + 1] : 0;
    int v2 = (base + 2 < N) ? cnt[base + 2] : 0;
    int v3 = (base + 3 < N) ? cnt[base + 3] : 0;
    tsum[t] = v0 + v1 + v2 + v3;
    __syncthreads();
    for (int off = 1; off < 256; off <<= 1) {
        int x = (t >= off) ? tsum[t - off] : 0;
        __syncthreads();
        if (t >= off) tsum[t] += x;
        __syncthreads();
    }
    int run = (t > 0) ? tsum[t - 1] : 0;
    if (base + 0 < N) seg[base + 0] = run; run += v0;
    if (base + 1 < N) seg[base + 1] = run; run += v1;
    if (base + 2 < N) seg[base + 2] = run; run += v2;
    if (base + 3 < N) seg[base + 3] = run;
    if (t == 255) bsums[blockIdx.x] = tsum[255];
}

__global__ void scan2_kernel(int* __restrict__ bsums, int* __restrict__ seg, int N, int G) {
    __shared__ int s[256];
    int t = threadIdx.x;
    if (t < G) s[t] = bsums[t];
    __syncthreads();
    if (t == 0) {
        int run = 0;
        for (int i = 0; i < G; ++i) { int v = s[i]; s[i] = run; run += v; }
        seg[N] = run;
    }
    __syncthreads();
    if (t < G) bsums[t] = s[t];
}

__global__ __launch_bounds__(256) void scan3_kernel(int* __restrict__ seg,
                                                    const int* __restrict__ bsums, int N) {
    int add = bsums[blockIdx.x];
    int base = blockIdx.x * 1024 + threadIdx.x * 4;
#pragma unroll
    for (int i = 0; i < 4; ++i) {
        int idx = base + i;
        if (idx < N) seg[idx] += add;
    }
}

// ---------------- P1c: LDS-staged partition scatter (both sides) ----------------
// Bucket id recorded at scatter time -> writeout has ZERO binary searches.
// Round-9: int4-vectorized staging loads (same mechanism as p1a).
__global__ __launch_bounds__(256) void p1c_kernel(const int* __restrict__ src, const int* __restrict__ dst,
                                                  const int* __restrict__ mat,
                                                  const int* __restrict__ scan,
                                                  int* __restrict__ pedge,
                                                  int E, int B1, int nbuk) {
    __shared__ int hd[NBUK_MAX], hs[NBUK_MAX];
    __shared__ int curD[NBUK_MAX], curS[NBUK_MAX];
    __shared__ int baseD[NBUK_MAX], baseS[NBUK_MAX];
    __shared__ int stD[CH];
    __shared__ int stS[CH];
    __shared__ unsigned char bkD[CH];
    const int t = threadIdx.x;
    if (t < nbuk) {
        hd[t] = mat[t * B1 + blockIdx.x];
        hs[t] = mat[(nbuk + t) * B1 + blockIdx.x];
    }
    const int base = blockIdx.x * CH;
    const int cnt = min(CH, E - base);
    int4 dl4[4], sl4[4];
    if (cnt == CH) {
        const int4* S4 = (const int4*)(src + base);
        const int4* D4 = (const int4*)(dst + base);
#pragma unroll
        for (int k = 0; k < 4; ++k) {
            dl4[k] = D4[t + k * 256];
            sl4[k] = S4[t + k * 256];
        }
    } else {
#pragma unroll
        for (int k = 0; k < 4; ++k) {
            int ib = k * 1024 + t * 4;
            dl4[k].x = (ib + 0 < cnt) ? dst[base + ib + 0] : 0;
            dl4[k].y = (ib + 1 < cnt) ? dst[base + ib + 1] : 0;
            dl4[k].z = (ib + 2 < cnt) ? dst[base + ib + 2] : 0;
            dl4[k].w = (ib + 3 < cnt) ? dst[base + ib + 3] : 0;
            sl4[k].x = (ib + 0 < cnt) ? src[base + ib + 0] : 0;
            sl4[k].y = (ib + 1 < cnt) ? src[base + ib + 1] : 0;
            sl4[k].z = (ib + 2 < cnt) ? src[base + ib + 2] : 0;
            sl4[k].w = (ib + 3 < cnt) ? src[base + ib + 3] : 0;
        }
    }
    __syncthreads();
    for (int off = 1; off < nbuk; off <<= 1) {
        int v0 = (t >= off && t < nbuk) ? hd[t - off] : 0;
        int w0 = (t >= off && t < nbuk) ? hs[t - off] : 0;
        __syncthreads();
        if (t < nbuk) { hd[t] += v0; hs[t] += w0; }
        __syncthreads();
    }
    if (t < nbuk) {
        int excD = t ? hd[t - 1] : 0;
        int excS = t ? hs[t - 1] : 0;
        curD[t] = excD;
        curS[t] = excS;
        baseD[t] = scan[t * B1 + blockIdx.x] - excD;
        baseS[t] = scan[(nbuk + t) * B1 + blockIdx.x] - excS;
    }
    __syncthreads();
#define P1C_PUT(dv, sv) { \
        int jj = (dv) >> 9; \
        int pp = atomicAdd(&curD[jj], 1); \
        stD[pp] = (((dv) & 511) << SRC_BITS) | (sv); \
        bkD[pp] = (unsigned char)jj; \
        int jq = (sv) >> 9; \
        int qq = atomicAdd(&curS[jq], 1); \
        stS[qq] = (sv) | (jq << SRC_BITS); \
    }
#pragma unroll
    for (int k = 0; k < 4; ++k) {
        int ib = k * 1024 + t * 4;
        if (ib + 3 < cnt) {
            P1C_PUT(dl4[k].x, sl4[k].x);
            P1C_PUT(dl4[k].y, sl4[k].y);
            P1C_PUT(dl4[k].z, sl4[k].z);
            P1C_PUT(dl4[k].w, sl4[k].w);
        } else {
            if (ib + 0 < cnt) P1C_PUT(dl4[k].x, sl4[k].x);
            if (ib + 1 < cnt) P1C_PUT(dl4[k].y, sl4[k].y);
            if (ib + 2 < cnt) P1C_PUT(dl4[k].z, sl4[k].z);
            if (ib + 3 < cnt) P1C_PUT(dl4[k].w, sl4[k].w);
        }
    }
#undef P1C_PUT
    __syncthreads();
    for (int i = t; i < cnt; i += 256) {
        int b = bkD[i];
        pedge[baseD[b] + i] = stD[i];
        int v = stS[i];
        pedge[baseS[v >> SRC_BITS] + i] = v;
    }
}

// ---------------- P2+S2 merged: per-bucket sort / histograms ----------------
// blocks [0, nbuk)       : P2 role — local sort -> esrc, seg, norm_dst
// blocks [nbuk, 2*nbuk)  : S2 role — src histogram -> norm_src
// Round-9: int4-vectorized pedge passes (4B-aligned dwordx4 — proven pattern).
__global__ __launch_bounds__(512) void p2s2_kernel(const int* __restrict__ pedge,
                                                   const int* __restrict__ scan,
                                                   int* __restrict__ esrc, int* __restrict__ seg,
                                                   float* __restrict__ norm_dst,
                                                   float* __restrict__ norm_src,
                                                   int N, int E, int B1, int nbuk) {
    __shared__ int h[512];
    __shared__ int cur[512];
    __shared__ int stage[MAXB];
    const int t = threadIdx.x;
    const int b0 = blockIdx.x;
    if (b0 >= nbuk) {
        // ---- S2 role ----
        const int b = b0 - nbuk;
        h[t] = 0;
        __syncthreads();
        const int sb0 = scan[(nbuk + b) * B1];
        const int sb1 = scan[(nbuk + b + 1) * B1];
        for (int i = sb0 + t * 4; i < sb1; i += 2048) {
            if (i + 3 < sb1) {
                int4 v = *(const int4*)&pedge[i];
                atomicAdd(&h[v.x & 511], 1);
                atomicAdd(&h[v.y & 511], 1);
                atomicAdd(&h[v.z & 511], 1);
                atomicAdd(&h[v.w & 511], 1);
            } else {
                for (int jt = i; jt < sb1; ++jt) atomicAdd(&h[pedge[jt] & 511], 1);
            }
        }
        __syncthreads();
        int n = (b << 9) + t;
        if (n < N) norm_src[n] = rsqrtf(fmaxf((float)h[t], 1.0f));
        return;
    }
    // ---- P2 role ----
    const int b = b0;
    h[t] = 0;
    __syncthreads();
    const int bb0 = scan[b * B1];
    const int bb1 = scan[(b + 1) * B1];
    for (int i = bb0 + t * 4; i < bb1; i += 2048) {
        if (i + 3 < bb1) {
            int4 v = *(const int4*)&pedge[i];
            atomicAdd(&h[(v.x >> SRC_BITS) & 511], 1);
            atomicAdd(&h[(v.y >> SRC_BITS) & 511], 1);
            atomicAdd(&h[(v.z >> SRC_BITS) & 511], 1);
            atomicAdd(&h[(v.w >> SRC_BITS) & 511], 1);
        } else {
            for (int jt = i; jt < bb1; ++jt) atomicAdd(&h[(pedge[jt] >> SRC_BITS) & 511], 1);
        }
    }
    __syncthreads();
    for (int off = 1; off < 512; off <<= 1) {
        int v = (t >= off) ? h[t - off] : 0;
        __syncthreads();
        h[t] += v;
        __syncthreads();
    }
    {
        int exc = t ? h[t - 1] : 0;
        cur[t] = exc;
        int n = (b << 9) + t;
        if (n < N) {
            seg[n] = bb0 + exc;
            norm_dst[n] = rsqrtf(fmaxf((float)(h[t] - exc), 1.0f));
        }
        if (b == 0 && t == 0) seg[N] = E;
    }
    __syncthreads();
    const int cnt = bb1 - bb0;
#define P2_SORT1(vv) { \
        int jj = ((vv) >> SRC_BITS) & 511; \
        int pp = atomicAdd(&cur[jj], 1); \
        int ss = (vv) & ((1 << SRC_BITS) - 1); \
        if (pp < MAXB) stage[pp] = ss; else esrc[bb0 + pp] = ss; \
    }
    for (int i = bb0 + t * 4; i < bb1; i += 2048) {
        if (i + 3 < bb1) {
            int4 v = *(const int4*)&pedge[i];
            P2_SORT1(v.x);
            P2_SORT1(v.y);
            P2_SORT1(v.z);
            P2_SORT1(v.w);
        } else {
            for (int jt = i; jt < bb1; ++jt) P2_SORT1(pedge[jt]);
        }
    }
#undef P2_SORT1
    __syncthreads();
    const int lim = min(cnt, MAXB);
    for (int i = t * 4; i < lim; i += 2048) {
        if (i + 3 < lim) {
            int4 v = *(const int4*)&stage[i];
            *(int4*)&esrc[bb0 + i] = v;   // 4B-aligned dwordx4 store
        } else {
            for (int jt = i; jt < lim; ++jt) esrc[bb0 + jt] = stage[jt];
        }
    }
}

// ---------------- X(bf16) = (H @ W) * norm_row  — MFMA split-bf16 ----------------
// Row-major X (128 B/row = one cache line: 8 feature-lanes coalesce to ONE line
// per edge in segsum — round-4 lesson: chunk-split layouts 8x the request count).
// Row N (one past the real nodes) is all-zero: segsum's masked slots redirect to it.
template<int K>
__global__ __launch_bounds__(256) void gemm_norm(const float* __restrict__ H,
                                                 const float* __restrict__ W,
                                                 const float* __restrict__ norm,
                                                 unsigned short* __restrict__ X, int N) {
    constexpr int KP = K + 8;  // padded stride (halves)
    __shared__ __align__(16) unsigned short sHi[64 * KP];
    __shared__ __align__(16) unsigned short sLo[64 * KP];
    const int tid = threadIdx.x;

    // stage W (row-major [K][64]) transposed, split hi/lo
    for (int idx = tid; idx < K * 64; idx += 256) {
        int k = idx >> 6;
        int c = idx & 63;
        float v = W[idx];
        unsigned short hi = f2bf(v);
        sHi[c * KP + k] = hi;
        sLo[c * KP + k] = f2bf(v - bf2f(hi));
    }
    __syncthreads();

    const int w = tid >> 6;
    const int lane = tid & 63;
    const int quad = lane >> 4;
    const int l16 = lane & 15;
    const int n0 = blockIdx.x * 64;
    const int arow = n0 + w * 16 + l16;
    const int arow_c = (arow < N) ? arow : (N - 1);
    const float* Hrow = H + (size_t)arow_c * K + quad * 8;

    f32x4 acc[4];
#pragma unroll
    for (int t = 0; t < 4; ++t) acc[t] = (f32x4){0.0f, 0.0f, 0.0f, 0.0f};

    float4 p0 = *(const float4*)(Hrow + 0);
    float4 p1 = *(const float4*)(Hrow + 4);

#pragma unroll
    for (int kc = 0; kc < K / 32; ++kc) {
        const float v[8] = {p0.x, p0.y, p0.z, p0.w, p1.x, p1.y, p1.z, p1.w};
        bf16x8 aHi, aLo;
#pragma unroll
        for (int j = 0; j < 8; ++j) {
            unsigned short hi = f2bf(v[j]);
            aHi[j] = (short)hi;
            aLo[j] = (short)f2bf(v[j] - bf2f(hi));
        }
        if (kc + 1 < K / 32) {
            p0 = *(const float4*)(Hrow + (kc + 1) * 32 + 0);
            p1 = *(const float4*)(Hrow + (kc + 1) * 32 + 4);
        }
        const int kbase = kc * 32 + quad * 8;
#pragma unroll
        for (int t = 0; t < 4; ++t) {
            const int col = t * 16 + l16;
            const bf16x8 bHi = *(const bf16x8*)&sHi[col * KP + kbase];
            const bf16x8 bLo = *(const bf16x8*)&sLo[col * KP + kbase];
            acc[t] = __builtin_amdgcn_mfma_f32_16x16x32_bf16(aLo, bHi, acc[t], 0, 0, 0);
            acc[t] = __builtin_amdgcn_mfma_f32_16x16x32_bf16(aHi, bLo, acc[t], 0, 0, 0);
            acc[t] = __builtin_amdgcn_mfma_f32_16x16x32_bf16(aHi, bHi, acc[t], 0, 0, 0);
        }
    }

#pragma unroll
    for (int r = 0; r < 4; ++r) {
        const int node = n0 + w * 16 + quad * 4 + r;
        if (node < N) {
            const float s = norm[node];
#pragma unroll
            for (int t = 0; t < 4; ++t) {
                X[(size_t)node * 64 + t * 16 + l16] = f2bf(acc[t][r] * s);
            }
        } else if (node == N) {
            // zero row for segsum's masked-slot redirect
#pragma unroll
            for (int t = 0; t < 4; ++t) {
                X[(size_t)node * 64 + t * 16 + l16] = 0;
            }
        }
    }
}

// ---------------- segment sum over CSR (bf16 X rows) + fused epilogue ----------------
// 1 node per wave (zero divergence). FLAT-32 with VECTOR esrc read: slot eh owns
// 4 consecutive edges loaded as one uint4 (dwordx4) -> 1 index load + 4 independent
// masked-redirect row gathers per pass. deg ~ Poisson(16): one pass covers ~all nodes.
// Out-of-range slots gather the L1-hot zero row X[N].
// Epilogue: 3-stage reduce-scatter -> each lane owns one feature -> coalesced store.
template<bool ELU>
__global__ __launch_bounds__(256) void segsum_kernel(const unsigned short* __restrict__ X,
                                                     const int* __restrict__ esrc,
                                                     const int* __restrict__ seg,
                                                     const float* __restrict__ norm_dst,
                                                     const float* __restrict__ bias,
                                                     float* __restrict__ out, int N) {
    const int node = __builtin_amdgcn_readfirstlane(blockIdx.x * 4 + (threadIdx.x >> 6));
    if (node >= N) return;
    const int lane = threadIdx.x & 63;
    const int eh = lane >> 3;          // edge slot 0..7 (owns 4 consecutive edges)
    const int fl = lane & 7;           // feature group (8 bf16 = 16 B)
    const unsigned flo = (unsigned)fl << 4;
    // feature this lane will own after reduce-scatter (bit-reversed eh)
    const int fown = fl * 8 + ((eh & 1) << 2) + (eh & 2) + (eh >> 2);
    const float bv = bias[fown];
    const int s0 = seg[node];
    const int s1 = seg[node + 1];
    const char* Xb = (const char*)X;
    f32x2 A0 = {0.0f, 0.0f}, A1 = {0.0f, 0.0f}, A2 = {0.0f, 0.0f}, A3 = {0.0f, 0.0f};
#define ACC8(u) \
    A0 += (f32x2){bflo(u.x), bfhi(u.x)}; A1 += (f32x2){bflo(u.y), bfhi(u.y)}; \
    A2 += (f32x2){bflo(u.z), bfhi(u.z)}; A3 += (f32x2){bflo(u.w), bfhi(u.w)};
    int e = s0;
    while (true) {
        const int b4 = e + eh * 4;
        const uint4 q = *(const uint4*)&esrc[b4];   // 4B-aligned dwordx4; esrc padded
        const int r0 = (b4 + 0 < s1) ? (int)q.x : N;
        const int r1 = (b4 + 1 < s1) ? (int)q.y : N;
        const int r2 = (b4 + 2 < s1) ? (int)q.z : N;
        const int r3 = (b4 + 3 < s1) ? (int)q.w : N;
        const uint4 u0 = *(const uint4*)(Xb + ((((unsigned)r0) << 7) | flo));
        const uint4 u1 = *(const uint4*)(Xb + ((((unsigned)r1) << 7) | flo));
        const uint4 u2 = *(const uint4*)(Xb + ((((unsigned)r2) << 7) | flo));
        const uint4 u3 = *(const uint4*)(Xb + ((((unsigned)r3) << 7) | flo));
        ACC8(u0);
        ACC8(u1);
        ACC8(u2);
        ACC8(u3);
        e += 32;
        if (e >= s1) break;
    }
#undef ACC8
    // reduce-scatter across the 8 slots: 3 stages, each lane keeps a shrinking set
    float a0 = A0.x, a1 = A0.y, a2 = A1.x, a3 = A1.y;
    float a4 = A2.x, a5 = A2.y, a6 = A3.x, a7 = A3.y;
    const bool p0 = (eh & 1) != 0;
    const bool p1 = (eh & 2) != 0;
    const bool p2 = (eh & 4) != 0;
    float t0, t1, t2, t3;
    {
        float sA = p0 ? a0 : a4, kA = p0 ? a4 : a0;
        float sB = p0 ? a1 : a5, kB = p0 ? a5 : a1;
        float sC = p0 ? a2 : a6, kC = p0 ? a6 : a2;
        float sD = p0 ? a3 : a7, kD = p0 ? a7 : a3;
        t0 = kA + __shfl_xor(sA, 8);
        t1 = kB + __shfl_xor(sB, 8);
        t2 = kC + __shfl_xor(sC, 8);
        t3 = kD + __shfl_xor(sD, 8);
    }
    float u0, u1;
    {
        float sA = p1 ? t0 : t2, kA = p1 ? t2 : t0;
        float sB = p1 ? t1 : t3, kB = p1 ? t3 : t1;
        u0 = kA + __shfl_xor(sA, 16);
        u1 = kB + __shfl_xor(sB, 16);
    }
    float v;
    {
        float sA = p2 ? u0 : u1, kA = p2 ? u1 : u0;
        v = kA + __shfl_xor(sA, 32);
    }
    // epilogue: every lane handles exactly one feature
    const float s = norm_dst[node];
    float r = v * s + bv;
    if (ELU) r = r > 0.0f ? r : expm1f(r);
    out[(size_t)node * 64 + fown] = r;
}

extern "C" void kernel_launch(void* const* d_in, const int* in_sizes, int n_in,
                              void* d_out, int out_size, void* d_ws, size_t ws_size,
                              hipStream_t stream) {
    const float* h   = (const float*)d_in[0];
    const int*   src = (const int*)d_in[1];
    const int*   dst = (const int*)d_in[2];
    const float* W1  = (const float*)d_in[3];
    const float* b1  = (const float*)d_in[4];
    const float* W2  = (const float*)d_in[5];
    const float* b2  = (const float*)d_in[6];
    float* out = (float*)d_out;

    const int N = in_sizes[0] / 128;       // 100000
    const int E = in_sizes[1];             // 1600000
    const int nbuk = (N + 511) >> 9;       // 196
    const int B1 = (E + CH - 1) / CH;      // 391
    const int M = 2 * nbuk * B1;

    int* iw = (int*)d_ws;
    int* mat   = iw;                       // M
    int* scanb = mat + M;                  // M+4
    int* bsums = scanb + M + 4;            // 256
    int* pedge = bsums + 256;              // 2E
    int* esrc  = pedge + 2 * (size_t)E;    // E (+40 pad for flat-32 over-read)
    int* seg   = esrc + (size_t)E + 40;    // N+1 (+pad)
    uintptr_t fp = (uintptr_t)(seg + (size_t)N + 4);
    fp = (fp + 63) & ~(uintptr_t)63;
    float* norm_src = (float*)fp;                      // N
    float* norm_dst = norm_src + (size_t)N;            // N
    float* H1       = norm_dst + (size_t)N;            // 64N floats
    unsigned short* Xb = (unsigned short*)(H1 + 64 * (size_t)N);  // 64(N+1) bf16

    // ---- CSR build ----
    p1a_kernel<<<B1, 256, 0, stream>>>(src, dst, mat, E, B1, nbuk);
    const int G = (M + 1023) / 1024;
    scan1_kernel<<<G, 256, 0, stream>>>(mat, scanb, bsums, M);
    scan2_kernel<<<1, 256, 0, stream>>>(bsums, scanb, M, G);
    scan3_kernel<<<G, 256, 0, stream>>>(scanb, bsums, M);
    p1c_kernel<<<B1, 256, 0, stream>>>(src, dst, mat, scanb, pedge, E, B1, nbuk);
    p2s2_kernel<<<2 * nbuk, 512, 0, stream>>>(pedge, scanb, esrc, seg, norm_dst, norm_src,
                                              N, E, B1, nbuk);

    const int segGrid = (N + 3) / 4;
    const int gemmGrid = (N + 64) / 64;    // +1 so the zero row (node==N) is always written

    // ---- layer 1 ----
    gemm_norm<128><<<gemmGrid, 256, 0, stream>>>(h, W1, norm_src, Xb, N);
    segsum_kernel<true><<<segGrid, 256, 0, stream>>>(Xb, esrc, seg, norm_dst, b1, H1, N);

    // ---- layer 2 ----
    gemm_norm<64><<<gemmGrid, 256, 0, stream>>>(H1, W2, norm_src, Xb, N);
    segsum_kernel<false><<<segGrid, 256, 0, stream>>>(Xb, esrc, seg, norm_dst, b2, out, N);
}

// Round 11
// 235.792 us; speedup vs baseline: 1.1213x; 1.0036x over previous
//
#include <hip/hip_runtime.h>
#include <math.h>

#define CH 4096        // edges per partition block
#define NBUK_MAX 256   // max buckets (N <= 131072)
#define HP 264         // histogram copy stride (264 % 32 = 8 -> copies 8 banks apart)
#define MAXB 12288     // max edges per bucket staged in LDS (48 KB)
#define SRC_BITS 17    // N < 131072 fits in 17 bits

typedef short bf16x8 __attribute__((ext_vector_type(8)));
typedef float f32x4 __attribute__((ext_vector_type(4)));
typedef float f32x2 __attribute__((ext_vector_type(2)));

// bf16 <-> f32 helpers (RNE pack; exact unpack)
__device__ __forceinline__ unsigned short f2bf(float f) {
    union { float f; unsigned int u; } v; v.f = f;
    unsigned int r = (v.u + 0x7FFFu + ((v.u >> 16) & 1u)) >> 16;
    return (unsigned short)r;
}
__device__ __forceinline__ float bf2f(unsigned short u) {
    union { unsigned int u; float f; } v; v.u = ((unsigned int)u) << 16;
    return v.f;
}
// unpack packed pair (low ushort = even feature, high = odd)
__device__ __forceinline__ float bflo(unsigned int u) {
    union { unsigned int u; float f; } v; v.u = u << 16;
    return v.f;
}
__device__ __forceinline__ float bfhi(unsigned int u) {
    union { unsigned int u; float f; } v; v.u = u & 0xFFFF0000u;
    return v.f;
}

// ---------------- P1a: per-block bucket histograms (dst + src, LDS only) ----------------
// Round-2 lesson: NO global atomicAdd(&deg[src],1). Round-7 lesson: keep the
// separated scan pipeline. Round-11: 4-way LANE-indexed sub-histograms (lane&3)
// — within-wave same-address LDS atomics serialize; 16 lanes/copy into 196 bins
// is near collision-free (old wave-parity split did nothing within a wave).
__global__ __launch_bounds__(256) void p1a_kernel(const int* __restrict__ src, const int* __restrict__ dst,
                                                  int* __restrict__ mat, int E, int B1, int nbuk) {
    __shared__ int hd[4][HP], hs[4][HP];
    const int t = threadIdx.x;
    const int c4 = t & 3;   // lane-derived copy index
    for (int i = t; i < 4 * HP; i += 256) { ((int*)hd)[i] = 0; ((int*)hs)[i] = 0; }
    __syncthreads();
    const int base = blockIdx.x * CH;
    const int cnt = min(CH, E - base);
    if (cnt == CH) {
        const int4* S4 = (const int4*)(src + base);
        const int4* D4 = (const int4*)(dst + base);
        int4 d0 = D4[t], d1 = D4[t + 256], d2 = D4[t + 512], d3 = D4[t + 768];
        int4 s0 = S4[t], s1 = S4[t + 256], s2 = S4[t + 512], s3 = S4[t + 768];
        atomicAdd(&hd[c4][d0.x >> 9], 1); atomicAdd(&hd[c4][d0.y >> 9], 1);
        atomicAdd(&hd[c4][d0.z >> 9], 1); atomicAdd(&hd[c4][d0.w >> 9], 1);
        atomicAdd(&hd[c4][d1.x >> 9], 1); atomicAdd(&hd[c4][d1.y >> 9], 1);
        atomicAdd(&hd[c4][d1.z >> 9], 1); atomicAdd(&hd[c4][d1.w >> 9], 1);
        atomicAdd(&hd[c4][d2.x >> 9], 1); atomicAdd(&hd[c4][d2.y >> 9], 1);
        atomicAdd(&hd[c4][d2.z >> 9], 1); atomicAdd(&hd[c4][d2.w >> 9], 1);
        atomicAdd(&hd[c4][d3.x >> 9], 1); atomicAdd(&hd[c4][d3.y >> 9], 1);
        atomicAdd(&hd[c4][d3.z >> 9], 1); atomicAdd(&hd[c4][d3.w >> 9], 1);
        atomicAdd(&hs[c4][s0.x >> 9], 1); atomicAdd(&hs[c4][s0.y >> 9], 1);
        atomicAdd(&hs[c4][s0.z >> 9], 1); atomicAdd(&hs[c4][s0.w >> 9], 1);
        atomicAdd(&hs[c4][s1.x >> 9], 1); atomicAdd(&hs[c4][s1.y >> 9], 1);
        atomicAdd(&hs[c4][s1.z >> 9], 1); atomicAdd(&hs[c4][s1.w >> 9], 1);
        atomicAdd(&hs[c4][s2.x >> 9], 1); atomicAdd(&hs[c4][s2.y >> 9], 1);
        atomicAdd(&hs[c4][s2.z >> 9], 1); atomicAdd(&hs[c4][s2.w >> 9], 1);
        atomicAdd(&hs[c4][s3.x >> 9], 1); atomicAdd(&hs[c4][s3.y >> 9], 1);
        atomicAdd(&hs[c4][s3.z >> 9], 1); atomicAdd(&hs[c4][s3.w >> 9], 1);
    } else {
        for (int k = t; k < cnt; k += 256) {
            int d = dst[base + k];
            int s = src[base + k];
            atomicAdd(&hd[c4][d >> 9], 1);
            atomicAdd(&hs[c4][s >> 9], 1);
        }
    }
    __syncthreads();
    if (t < nbuk) {
        mat[t * B1 + blockIdx.x] = hd[0][t] + hd[1][t] + hd[2][t] + hd[3][t];
        mat[(nbuk + t) * B1 + blockIdx.x] = hs[0][t] + hs[1][t] + hs[2][t] + hs[3][t];
    }
}

// ---------------- 3-phase exclusive scan ----------------
__global__ __launch_bounds__(256) void scan1_kernel(const int* __restrict__ cnt,
                                                    int* __restrict__ seg,
                                                    int* __restrict__ bsums, int N) {
    __shared__ int tsum[256];
    const int t = threadIdx.x;
    const int base = blockIdx.x * 1024 + t * 4;
    int v0 = (base + 0 < N) ? cnt[base + 0] : 0;
    int v1 = (base + 1 < N) ? cnt[base + 1] : 0;
    int v2 = (base + 2 < N) ? cnt[base + 2] : 0;
    int v3 = (base + 3 < N) ? cnt[base + 3] : 0;
    tsum[t] = v0 + v1 + v2 + v3;
    __syncthreads();
    for (int off = 1; off < 256; off <<= 1) {
        int x = (t >= off) ? tsum[t - off] : 0;
        __syncthreads();
        if (t >= off) tsum[t] += x;
        __syncthreads();
    }
    int run = (t > 0) ? tsum[t - 1] : 0;
    if (base + 0 < N) seg[base + 0] = run; run += v0;
    if (base + 1 < N) seg[base + 1] = run; run += v1;
    if (base + 2 < N) seg[base + 2] = run; run += v2;
    if (base + 3 < N) seg[base + 3] = run;
    if (t == 255) bsums[blockIdx.x] = tsum[255];
}

__global__ void scan2_kernel(int* __restrict__ bsums, int* __restrict__ seg, int N, int G) {
    __shared__ int s[256];
    int t = threadIdx.x;
    if (t < G) s[t] = bsums[t];
    __syncthreads();
    if (t == 0) {
        int run = 0;
        for (int i = 0; i < G; ++i) { int v = s[i]; s[i] = run; run += v; }
        seg[N] = run;
    }
    __syncthreads();
    if (t < G) bsums[t] = s[t];
}

__global__ __launch_bounds__(256) void scan3_kernel(int* __restrict__ seg,
                                                    const int* __restrict__ bsums, int N) {
    int add = bsums[blockIdx.x];
    int base = blockIdx.x * 1024 + threadIdx.x * 4;
#pragma unroll
    for (int i = 0; i < 4; ++i) {
        int idx = base + i;
        if (idx < N) seg[idx] += add;
    }
}

// ---------------- P1c: LDS-staged partition scatter (both sides) ----------------
// Bucket id recorded at scatter time -> writeout has ZERO binary searches.
// Round-11: vectorized writeout — b128 LDS reads + int4 global stores when the
// 4-run is bucket-uniform (~94% at ~21-edge mean runs). Global dwordx4 needs only
// 4 B alignment on CDNA (pattern proven in segsum's esrc read).
__global__ __launch_bounds__(256) void p1c_kernel(const int* __restrict__ src, const int* __restrict__ dst,
                                                  const int* __restrict__ mat,
                                                  const int* __restrict__ scan,
                                                  int* __restrict__ pedge,
                                                  int E, int B1, int nbuk) {
    __shared__ int hd[NBUK_MAX], hs[NBUK_MAX];
    __shared__ int curD[NBUK_MAX], curS[NBUK_MAX];
    __shared__ int baseD[NBUK_MAX], baseS[NBUK_MAX];
    __shared__ __align__(16) int stD[CH];
    __shared__ __align__(16) int stS[CH];
    __shared__ __align__(4) unsigned char bkD[CH];
    const int t = threadIdx.x;
    if (t < nbuk) {
        hd[t] = mat[t * B1 + blockIdx.x];
        hs[t] = mat[(nbuk + t) * B1 + blockIdx.x];
    }
    const int base = blockIdx.x * CH;
    const int cnt = min(CH, E - base);
    int4 dl4[4], sl4[4];
    if (cnt == CH) {
        const int4* S4 = (const int4*)(src + base);
        const int4* D4 = (const int4*)(dst + base);
#pragma unroll
        for (int k = 0; k < 4; ++k) {
            dl4[k] = D4[t + k * 256];
            sl4[k] = S4[t + k * 256];
        }
    } else {
#pragma unroll
        for (int k = 0; k < 4; ++k) {
            int ib = k * 1024 + t * 4;
            dl4[k].x = (ib + 0 < cnt) ? dst[base + ib + 0] : 0;
            dl4[k].y = (ib + 1 < cnt) ? dst[base + ib + 1] : 0;
            dl4[k].z = (ib + 2 < cnt) ? dst[base + ib + 2] : 0;
            dl4[k].w = (ib + 3 < cnt) ? dst[base + ib + 3] : 0;
            sl4[k].x = (ib + 0 < cnt) ? src[base + ib + 0] : 0;
            sl4[k].y = (ib + 1 < cnt) ? src[base + ib + 1] : 0;
            sl4[k].z = (ib + 2 < cnt) ? src[base + ib + 2] : 0;
            sl4[k].w = (ib + 3 < cnt) ? src[base + ib + 3] : 0;
        }
    }
    __syncthreads();
    for (int off = 1; off < nbuk; off <<= 1) {
        int v0 = (t >= off && t < nbuk) ? hd[t - off] : 0;
        int w0 = (t >= off && t < nbuk) ? hs[t - off] : 0;
        __syncthreads();
        if (t < nbuk) { hd[t] += v0; hs[t] += w0; }
        __syncthreads();
    }
    if (t < nbuk) {
        int excD = t ? hd[t - 1] : 0;
        int excS = t ? hs[t - 1] : 0;
        curD[t] = excD;
        curS[t] = excS;
        baseD[t] = scan[t * B1 + blockIdx.x] - excD;
        baseS[t] = scan[(nbuk + t) * B1 + blockIdx.x] - excS;
    }
    __syncthreads();
#define P1C_PUT(dv, sv) { \
        int jj = (dv) >> 9; \
        int pp = atomicAdd(&curD[jj], 1); \
        stD[pp] = (((dv) & 511) << SRC_BITS) | (sv); \
        bkD[pp] = (unsigned char)jj; \
        int jq = (sv) >> 9; \
        int qq = atomicAdd(&curS[jq], 1); \
        stS[qq] = (sv) | (jq << SRC_BITS); \
    }
#pragma unroll
    for (int k = 0; k < 4; ++k) {
        int ib = k * 1024 + t * 4;
        if (ib + 3 < cnt) {
            P1C_PUT(dl4[k].x, sl4[k].x);
            P1C_PUT(dl4[k].y, sl4[k].y);
            P1C_PUT(dl4[k].z, sl4[k].z);
            P1C_PUT(dl4[k].w, sl4[k].w);
        } else {
            if (ib + 0 < cnt) P1C_PUT(dl4[k].x, sl4[k].x);
            if (ib + 1 < cnt) P1C_PUT(dl4[k].y, sl4[k].y);
            if (ib + 2 < cnt) P1C_PUT(dl4[k].z, sl4[k].z);
            if (ib + 3 < cnt) P1C_PUT(dl4[k].w, sl4[k].w);
        }
    }
#undef P1C_PUT
    __syncthreads();
    for (int i = t * 4; i < cnt; i += 1024) {
        if (i + 3 < cnt) {
            // dst side: 4-run uniform-bucket check via packed uchar4
            unsigned bw = *(const unsigned*)&bkD[i];
            int4 sd = *(const int4*)&stD[i];     // LDS b128 (16B-aligned)
            if (bw == (bw & 0xFFu) * 0x01010101u) {
                *(int4*)&pedge[baseD[bw & 0xFFu] + i] = sd;
            } else {
                pedge[baseD[(bw >> 0) & 0xFFu] + i + 0] = sd.x;
                pedge[baseD[(bw >> 8) & 0xFFu] + i + 1] = sd.y;
                pedge[baseD[(bw >> 16) & 0xFFu] + i + 2] = sd.z;
                pedge[baseD[(bw >> 24) & 0xFFu] + i + 3] = sd.w;
            }
            // src side: bucket packed in high bits of the entry itself
            int4 ss = *(const int4*)&stS[i];
            int c0 = ss.x >> SRC_BITS, c1 = ss.y >> SRC_BITS;
            int c2 = ss.z >> SRC_BITS, c3 = ss.w >> SRC_BITS;
            if (c0 == c1 && c0 == c2 && c0 == c3) {
                *(int4*)&pedge[baseS[c0] + i] = ss;
            } else {
                pedge[baseS[c0] + i + 0] = ss.x;
                pedge[baseS[c1] + i + 1] = ss.y;
                pedge[baseS[c2] + i + 2] = ss.z;
                pedge[baseS[c3] + i + 3] = ss.w;
            }
        } else {
            for (int jt = i; jt < cnt; ++jt) {
                pedge[baseD[bkD[jt]] + jt] = stD[jt];
                int v = stS[jt];
                pedge[baseS[v >> SRC_BITS] + jt] = v;
            }
        }
    }
}

// ---------------- P2+S2 merged: per-bucket sort / histograms ----------------
// blocks [0, nbuk)       : P2 role — local sort -> esrc, seg, norm_dst
// blocks [nbuk, 2*nbuk)  : S2 role — src histogram -> norm_src
__global__ __launch_bounds__(512) void p2s2_kernel(const int* __restrict__ pedge,
                                                   const int* __restrict__ scan,
                                                   int* __restrict__ esrc, int* __restrict__ seg,
                                                   float* __restrict__ norm_dst,
                                                   float* __restrict__ norm_src,
                                                   int N, int E, int B1, int nbuk) {
    __shared__ int h[512];
    __shared__ int cur[512];
    __shared__ __align__(16) int stage[MAXB];
    const int t = threadIdx.x;
    const int b0 = blockIdx.x;
    if (b0 >= nbuk) {
        // ---- S2 role ----
        const int b = b0 - nbuk;
        h[t] = 0;
        __syncthreads();
        const int sb0 = scan[(nbuk + b) * B1];
        const int sb1 = scan[(nbuk + b + 1) * B1];
        for (int i = sb0 + t * 4; i < sb1; i += 2048) {
            if (i + 3 < sb1) {
                int4 v = *(const int4*)&pedge[i];
                atomicAdd(&h[v.x & 511], 1);
                atomicAdd(&h[v.y & 511], 1);
                atomicAdd(&h[v.z & 511], 1);
                atomicAdd(&h[v.w & 511], 1);
            } else {
                for (int jt = i; jt < sb1; ++jt) atomicAdd(&h[pedge[jt] & 511], 1);
            }
        }
        __syncthreads();
        int n = (b << 9) + t;
        if (n < N) norm_src[n] = rsqrtf(fmaxf((float)h[t], 1.0f));
        return;
    }
    // ---- P2 role ----
    const int b = b0;
    h[t] = 0;
    __syncthreads();
    const int bb0 = scan[b * B1];
    const int bb1 = scan[(b + 1) * B1];
    for (int i = bb0 + t * 4; i < bb1; i += 2048) {
        if (i + 3 < bb1) {
            int4 v = *(const int4*)&pedge[i];
            atomicAdd(&h[(v.x >> SRC_BITS) & 511], 1);
            atomicAdd(&h[(v.y >> SRC_BITS) & 511], 1);
            atomicAdd(&h[(v.z >> SRC_BITS) & 511], 1);
            atomicAdd(&h[(v.w >> SRC_BITS) & 511], 1);
        } else {
            for (int jt = i; jt < bb1; ++jt) atomicAdd(&h[(pedge[jt] >> SRC_BITS) & 511], 1);
        }
    }
    __syncthreads();
    for (int off = 1; off < 512; off <<= 1) {
        int v = (t >= off) ? h[t - off] : 0;
        __syncthreads();
        h[t] += v;
        __syncthreads();
    }
    {
        int exc = t ? h[t - 1] : 0;
        cur[t] = exc;
        int n = (b << 9) + t;
        if (n < N) {
            seg[n] = bb0 + exc;
            norm_dst[n] = rsqrtf(fmaxf((float)(h[t] - exc), 1.0f));
        }
        if (b == 0 && t == 0) seg[N] = E;
    }
    __syncthreads();
    const int cnt = bb1 - bb0;
#define P2_SORT1(vv) { \
        int jj = ((vv) >> SRC_BITS) & 511; \
        int pp = atomicAdd(&cur[jj], 1); \
        int ss = (vv) & ((1 << SRC_BITS) - 1); \
        if (pp < MAXB) stage[pp] = ss; else esrc[bb0 + pp] = ss; \
    }
    for (int i = bb0 + t * 4; i < bb1; i += 2048) {
        if (i + 3 < bb1) {
            int4 v = *(const int4*)&pedge[i];
            P2_SORT1(v.x);
            P2_SORT1(v.y);
            P2_SORT1(v.z);
            P2_SORT1(v.w);
        } else {
            for (int jt = i; jt < bb1; ++jt) P2_SORT1(pedge[jt]);
        }
    }
#undef P2_SORT1
    __syncthreads();
    const int lim = min(cnt, MAXB);
    for (int i = t * 4; i < lim; i += 2048) {
        if (i + 3 < lim) {
            int4 v = *(const int4*)&stage[i];
            *(int4*)&esrc[bb0 + i] = v;   // 4B-aligned dwordx4 store
        } else {
            for (int jt = i; jt < lim; ++jt) esrc[bb0 + jt] = stage[jt];
        }
    }
}

// ---------------- X(bf16) = (H @ W) * norm_row  — MFMA split-bf16 ----------------
// Row-major X (128 B/row = one cache line: 8 feature-lanes coalesce to ONE line
// per edge in segsum — round-4 lesson: chunk-split layouts 8x the request count).
// Row N (one past the real nodes) is all-zero: segsum's masked slots redirect to it.
template<int K>
__global__ __launch_bounds__(256) void gemm_norm(const float* __restrict__ H,
                                                 const float* __restrict__ W,
                                                 const float* __restrict__ norm,
                                                 unsigned short* __restrict__ X, int N) {
    constexpr int KP = K + 8;  // padded stride (halves)
    __shared__ __align__(16) unsigned short sHi[64 * KP];
    __shared__ __align__(16) unsigned short sLo[64 * KP];
    const int tid = threadIdx.x;

    // stage W (row-major [K][64]) transposed, split hi/lo
    for (int idx = tid; idx < K * 64; idx += 256) {
        int k = idx >> 6;
        int c = idx & 63;
        float v = W[idx];
        unsigned short hi = f2bf(v);
        sHi[c * KP + k] = hi;
        sLo[c * KP + k] = f2bf(v - bf2f(hi));
    }
    __syncthreads();

    const int w = tid >> 6;
    const int lane = tid & 63;
    const int quad = lane >> 4;
    const int l16 = lane & 15;
    const int n0 = blockIdx.x * 64;
    const int arow = n0 + w * 16 + l16;
    const int arow_c = (arow < N) ? arow : (N - 1);
    const float* Hrow = H + (size_t)arow_c * K + quad * 8;

    f32x4 acc[4];
#pragma unroll
    for (int t = 0; t < 4; ++t) acc[t] = (f32x4){0.0f, 0.0f, 0.0f, 0.0f};

    float4 p0 = *(const float4*)(Hrow + 0);
    float4 p1 = *(const float4*)(Hrow + 4);

#pragma unroll
    for (int kc = 0; kc < K / 32; ++kc) {
        const float v[8] = {p0.x, p0.y, p0.z, p0.w, p1.x, p1.y, p1.z, p1.w};
        bf16x8 aHi, aLo;
#pragma unroll
        for (int j = 0; j < 8; ++j) {
            unsigned short hi = f2bf(v[j]);
            aHi[j] = (short)hi;
            aLo[j] = (short)f2bf(v[j] - bf2f(hi));
        }
        if (kc + 1 < K / 32) {
            p0 = *(const float4*)(Hrow + (kc + 1) * 32 + 0);
            p1 = *(const float4*)(Hrow + (kc + 1) * 32 + 4);
        }
        const int kbase = kc * 32 + quad * 8;
#pragma unroll
        for (int t = 0; t < 4; ++t) {
            const int col = t * 16 + l16;
            const bf16x8 bHi = *(const bf16x8*)&sHi[col * KP + kbase];
            const bf16x8 bLo = *(const bf16x8*)&sLo[col * KP + kbase];
            acc[t] = __builtin_amdgcn_mfma_f32_16x16x32_bf16(aLo, bHi, acc[t], 0, 0, 0);
            acc[t] = __builtin_amdgcn_mfma_f32_16x16x32_bf16(aHi, bLo, acc[t], 0, 0, 0);
            acc[t] = __builtin_amdgcn_mfma_f32_16x16x32_bf16(aHi, bHi, acc[t], 0, 0, 0);
        }
    }

#pragma unroll
    for (int r = 0; r < 4; ++r) {
        const int node = n0 + w * 16 + quad * 4 + r;
        if (node < N) {
            const float s = norm[node];
#pragma unroll
            for (int t = 0; t < 4; ++t) {
                X[(size_t)node * 64 + t * 16 + l16] = f2bf(acc[t][r] * s);
            }
        } else if (node == N) {
            // zero row for segsum's masked-slot redirect
#pragma unroll
            for (int t = 0; t < 4; ++t) {
                X[(size_t)node * 64 + t * 16 + l16] = 0;
            }
        }
    }
}

// ---------------- segment sum over CSR (bf16 X rows) + fused epilogue ----------------
// 1 node per wave (zero divergence). FLAT-32 with VECTOR esrc read: slot eh owns
// 4 consecutive edges loaded as one uint4 (dwordx4) -> 1 index load + 4 independent
// masked-redirect row gathers per pass. deg ~ Poisson(16): one pass covers ~all nodes.
// Out-of-range slots gather the L1-hot zero row X[N].
// Epilogue: 3-stage reduce-scatter -> each lane owns one feature -> coalesced store.
template<bool ELU>
__global__ __launch_bounds__(256) void segsum_kernel(const unsigned short* __restrict__ X,
                                                     const int* __restrict__ esrc,
                                                     const int* __restrict__ seg,
                                                     const float* __restrict__ norm_dst,
                                                     const float* __restrict__ bias,
                                                     float* __restrict__ out, int N) {
    const int node = __builtin_amdgcn_readfirstlane(blockIdx.x * 4 + (threadIdx.x >> 6));
    if (node >= N) return;
    const int lane = threadIdx.x & 63;
    const int eh = lane >> 3;          // edge slot 0..7 (owns 4 consecutive edges)
    const int fl = lane & 7;           // feature group (8 bf16 = 16 B)
    const unsigned flo = (unsigned)fl << 4;
    // feature this lane will own after reduce-scatter (bit-reversed eh)
    const int fown = fl * 8 + ((eh & 1) << 2) + (eh & 2) + (eh >> 2);
    const float bv = bias[fown];
    const int s0 = seg[node];
    const int s1 = seg[node + 1];
    const char* Xb = (const char*)X;
    f32x2 A0 = {0.0f, 0.0f}, A1 = {0.0f, 0.0f}, A2 = {0.0f, 0.0f}, A3 = {0.0f, 0.0f};
#define ACC8(u) \
    A0 += (f32x2){bflo(u.x), bfhi(u.x)}; A1 += (f32x2){bflo(u.y), bfhi(u.y)}; \
    A2 += (f32x2){bflo(u.z), bfhi(u.z)}; A3 += (f32x2){bflo(u.w), bfhi(u.w)};
    int e = s0;
    while (true) {
        const int b4 = e + eh * 4;
        const uint4 q = *(const uint4*)&esrc[b4];   // 4B-aligned dwordx4; esrc padded
        const int r0 = (b4 + 0 < s1) ? (int)q.x : N;
        const int r1 = (b4 + 1 < s1) ? (int)q.y : N;
        const int r2 = (b4 + 2 < s1) ? (int)q.z : N;
        const int r3 = (b4 + 3 < s1) ? (int)q.w : N;
        const uint4 u0 = *(const uint4*)(Xb + ((((unsigned)r0) << 7) | flo));
        const uint4 u1 = *(const uint4*)(Xb + ((((unsigned)r1) << 7) | flo));
        const uint4 u2 = *(const uint4*)(Xb + ((((unsigned)r2) << 7) | flo));
        const uint4 u3 = *(const uint4*)(Xb + ((((unsigned)r3) << 7) | flo));
        ACC8(u0);
        ACC8(u1);
        ACC8(u2);
        ACC8(u3);
        e += 32;
        if (e >= s1) break;
    }
#undef ACC8
    // reduce-scatter across the 8 slots: 3 stages, each lane keeps a shrinking set
    float a0 = A0.x, a1 = A0.y, a2 = A1.x, a3 = A1.y;
    float a4 = A2.x, a5 = A2.y, a6 = A3.x, a7 = A3.y;
    const bool p0 = (eh & 1) != 0;
    const bool p1 = (eh & 2) != 0;
    const bool p2 = (eh & 4) != 0;
    float t0, t1, t2, t3;
    {
        float sA = p0 ? a0 : a4, kA = p0 ? a4 : a0;
        float sB = p0 ? a1 : a5, kB = p0 ? a5 : a1;
        float sC = p0 ? a2 : a6, kC = p0 ? a6 : a2;
        float sD = p0 ? a3 : a7, kD = p0 ? a7 : a3;
        t0 = kA + __shfl_xor(sA, 8);
        t1 = kB + __shfl_xor(sB, 8);
        t2 = kC + __shfl_xor(sC, 8);
        t3 = kD + __shfl_xor(sD, 8);
    }
    float u0, u1;
    {
        float sA = p1 ? t0 : t2, kA = p1 ? t2 : t0;
        float sB = p1 ? t1 : t3, kB = p1 ? t3 : t1;
        u0 = kA + __shfl_xor(sA, 16);
        u1 = kB + __shfl_xor(sB, 16);
    }
    float v;
    {
        float sA = p2 ? u0 : u1, kA = p2 ? u1 : u0;
        v = kA + __shfl_xor(sA, 32);
    }
    // epilogue: every lane handles exactly one feature
    const float s = norm_dst[node];
    float r = v * s + bv;
    if (ELU) r = r > 0.0f ? r : expm1f(r);
    out[(size_t)node * 64 + fown] = r;
}

extern "C" void kernel_launch(void* const* d_in, const int* in_sizes, int n_in,
                              void* d_out, int out_size, void* d_ws, size_t ws_size,
                              hipStream_t stream) {
    const float* h   = (const float*)d_in[0];
    const int*   src = (const int*)d_in[1];
    const int*   dst = (const int*)d_in[2];
    const float* W1  = (const float*)d_in[3];
    const float* b1  = (const float*)d_in[4];
    const float* W2  = (const float*)d_in[5];
    const float* b2  = (const float*)d_in[6];
    float* out = (float*)d_out;

    const int N = in_sizes[0] / 128;       // 100000
    const int E = in_sizes[1];             // 1600000
    const int nbuk = (N + 511) >> 9;       // 196
    const int B1 = (E + CH - 1) / CH;      // 391
    const int M = 2 * nbuk * B1;

    int* iw = (int*)d_ws;
    int* mat   = iw;                       // M
    int* scanb = mat + M;                  // M+4
    int* bsums = scanb + M + 4;            // 256
    int* pedge = bsums + 256;              // 2E
    int* esrc  = pedge + 2 * (size_t)E;    // E (+40 pad for flat-32 over-read)
    int* seg   = esrc + (size_t)E + 40;    // N+1 (+pad)
    uintptr_t fp = (uintptr_t)(seg + (size_t)N + 4);
    fp = (fp + 63) & ~(uintptr_t)63;
    float* norm_src = (float*)fp;                      // N
    float* norm_dst = norm_src + (size_t)N;            // N
    float* H1       = norm_dst + (size_t)N;            // 64N floats
    unsigned short* Xb = (unsigned short*)(H1 + 64 * (size_t)N);  // 64(N+1) bf16

    // ---- CSR build ----
    p1a_kernel<<<B1, 256, 0, stream>>>(src, dst, mat, E, B1, nbuk);
    const int G = (M + 1023) / 1024;
    scan1_kernel<<<G, 256, 0, stream>>>(mat, scanb, bsums, M);
    scan2_kernel<<<1, 256, 0, stream>>>(bsums, scanb, M, G);
    scan3_kernel<<<G, 256, 0, stream>>>(scanb, bsums, M);
    p1c_kernel<<<B1, 256, 0, stream>>>(src, dst, mat, scanb, pedge, E, B1, nbuk);
    p2s2_kernel<<<2 * nbuk, 512, 0, stream>>>(pedge, scanb, esrc, seg, norm_dst, norm_src,
                                              N, E, B1, nbuk);

    const int segGrid = (N + 3) / 4;
    const int gemmGrid = (N + 64) / 64;    // +1 so the zero row (node==N) is always written

    // ---- layer 1 ----
    gemm_norm<128><<<gemmGrid, 256, 0, stream>>>(h, W1, norm_src, Xb, N);
    segsum_kernel<true><<<segGrid, 256, 0, stream>>>(Xb, esrc, seg, norm_dst, b1, H1, N);

    // ---- layer 2 ----
    gemm_norm<64><<<gemmGrid, 256, 0, stream>>>(H1, W2, norm_src, Xb, N);
    segsum_kernel<false><<<segGrid, 256, 0, stream>>>(Xb, esrc, seg, norm_dst, b2, out, N);
}